// Round 4
// baseline (138.960 us; speedup 1.0000x reference)
//
#include <hip/hip_runtime.h>
#include <hip/hip_bf16.h>
#include <stdint.h>

// Problem constants
#define Q_N   4096
#define D_N   32768
#define DIM   128
#define VOCAB 32000

#define NCHUNK 32                    // doc chunks
#define CHUNK  (D_N / NCHUNK)        // 1024 docs per chunk
#define QTILE  256                   // queries per block
#define NQT    (Q_N / QTILE)         // 16 q-tiles
#define DSUB   128                   // docs per LDS subtile
#define NSUB   (CHUNK / DSUB)        // 8 subtiles per chunk
#define NSLOT  (NCHUNK * 2)          // partial slots: chunk x wm-strip = 64

typedef short  short8 __attribute__((ext_vector_type(8)));
typedef float  f32x4  __attribute__((ext_vector_type(4)));

// Workspace layout (bytes)
#define WS_QBF  0u                               // 4096*128*2  = 1 MiB
#define WS_DBF  0x100000u                        // 32768*128*2 = 8 MiB
#define WS_PMI  0x900000u                        // 64*4096*8   = 2 MiB (float2: max, idx-bits)
#define WS_SUMS 0xB00000u                        // 4 floats

// ---------------- Kernel A: fp32 -> bf16 convert (+ zero sums) ----------------
__device__ inline ushort f2bf(float f) {
  uint32_t u = __float_as_uint(f);
  u += 0x7FFFu + ((u >> 16) & 1u);   // RNE
  return (ushort)(u >> 16);
}

__global__ void convert_kernel(const float* __restrict__ qe, const float* __restrict__ de,
                               ushort* __restrict__ qb, ushort* __restrict__ db,
                               float* __restrict__ sums) {
  int i = blockIdx.x * 256 + threadIdx.x;
  if (i < 4) sums[i] = 0.0f;         // ws is re-poisoned every launch
  const int NQ4 = Q_N * DIM / 4;     // 131072 float4s
  float4 v;
  ushort* dst;
  if (i < NQ4) {
    v = ((const float4*)qe)[i];
    dst = qb + (size_t)i * 4;
  } else {
    int j = i - NQ4;                 // < 1048576 (grid sized exactly)
    v = ((const float4*)de)[j];
    dst = db + (size_t)j * 4;
  }
  ushort4 o;
  o.x = f2bf(v.x); o.y = f2bf(v.y); o.z = f2bf(v.z); o.w = f2bf(v.w);
  *(ushort4*)dst = o;
}

// ---------------- Kernel B: MaxSim partial (GEMM + row-max/argmax epilogue) ----------------
// S^T tiles: M = docs, N = queries, K = 128. A = doc bf16 [D][128] (LDS-staged),
// B = query bf16 [Q][128] (registers). 512 threads = 8 waves as 2M x 4N over a
// 128-doc x 256-query tile: wm = wid>>2 (64-doc strip), wn = wid&3 (64-query strip).
// Per wave: mf in [0,4) A-frags, nf in [0,4) B-frags, kk in [0,4).
// mfma_f32_16x16x32_bf16 layouts (m89-verified):
//   A[m][k]: m = lane&15, k = (lane>>4)*8 + e
//   B[k][n]: n = lane&15, k = (lane>>4)*8 + e
//   C[r]:    col = lane&15, row = (lane>>4)*4 + r
// Block mapping concentrates each chunk's 16 q-tile blocks on ONE XCD so the
// 512 KB chunk (+1 MB q) stays L2-resident: xcd = bid&7 handles 4 chunks.
__global__ __launch_bounds__(512, 4)
void maxsim_kernel(const ushort* __restrict__ dbf, const ushort* __restrict__ qbf,
                   float2* __restrict__ pmi) {
  __shared__ ushort lds[2][DSUB * DIM];   // 2 x 32 KiB, double-buffered doc tile

  const int tid  = threadIdx.x;
  const int lane = tid & 63;
  const int wid  = tid >> 6;
  const int wm   = wid >> 2;              // doc strip: rows [wm*64, wm*64+64)
  const int wn   = wid & 3;               // query strip: cols [wn*64, wn*64+64)

  // XCD-concentrated (chunk, qtile) mapping: bijective over 512 blocks
  const int bid  = blockIdx.x;
  const int xcd  = bid & 7;
  const int slot = bid >> 3;              // [0,64)
  const int c    = xcd + 8 * (slot >> 4); // chunk id: 4 per XCD
  const int qt   = slot & 15;
  const int qblock = qt * QTILE;
  const int chunk0 = c * CHUNK;

  // ---- B fragments (queries) from global, held in registers: 64 VGPR ----
  short8 bfr[4][4];                       // [nf][kk]
  #pragma unroll
  for (int nf = 0; nf < 4; ++nf) {
    int qrow = qblock + wn * 64 + nf * 16 + (lane & 15);
    const ushort* p = qbf + (size_t)qrow * DIM + ((lane >> 4) * 8);
    #pragma unroll
    for (int kk = 0; kk < 4; ++kk)
      bfr[nf][kk] = *(const short8*)(p + kk * 32);
  }

  float rmax[4]; int ridx[4];
  #pragma unroll
  for (int nf = 0; nf < 4; ++nf) { rmax[nf] = -3.0e38f; ridx[nf] = 0; }

  const char* gdoc = (const char*)(dbf + (size_t)chunk0 * DIM);

  // Precomputed stage offsets (constant across subtiles).
  // LDS dest is linear (global_load_lds writes wave-uniform base + lane*16);
  // XOR swizzle (byte ^= ((row&7)<<4)) applied to GLOBAL source and on ds_read.
  int swzoff[4];
  #pragma unroll
  for (int it = 0; it < 4; ++it) {
    int o = wid * 4096 + it * 1024 + lane * 16;
    swzoff[it] = o ^ (((o >> 8) & 7) << 4);
  }

  auto stage = [&](int b, int st) {
    const char* gt = gdoc + st * (DSUB * DIM * 2);
    char* lb = (char*)&lds[b][0] + wid * 4096;
    #pragma unroll
    for (int it = 0; it < 4; ++it) {
      __builtin_amdgcn_global_load_lds(
          (const __attribute__((address_space(1))) uint32_t*)(gt + swzoff[it]),
          (__attribute__((address_space(3))) uint32_t*)(lb + it * 1024),
          16, 0, 0);
    }
  };

  stage(0, 0);
  __syncthreads();

  #pragma unroll 1
  for (int st = 0; st < NSUB; ++st) {     // 8 subtiles of 128 docs
    const int b = st & 1;
    if (st + 1 < NSUB) stage(b ^ 1, st + 1);

    const char* lb = (const char*)&lds[b][0];
    #pragma unroll
    for (int mf = 0; mf < 4; ++mf) {
      short8 afr[4];
      int arow = wm * 64 + mf * 16 + (lane & 15);
      #pragma unroll
      for (int kk = 0; kk < 4; ++kk) {
        int abyte = (arow * 256 + kk * 64 + ((lane >> 4) * 16)) ^ ((arow & 7) << 4);
        afr[kk] = *(const short8*)(lb + abyte);
      }
      // 4 independent accumulator chains (nf inner) pipeline the MFMA latency
      f32x4 acc[4];
      #pragma unroll
      for (int nf = 0; nf < 4; ++nf) acc[nf] = (f32x4){0.f, 0.f, 0.f, 0.f};
      #pragma unroll
      for (int kk = 0; kk < 4; ++kk)
        #pragma unroll
        for (int nf = 0; nf < 4; ++nf)
          acc[nf] = __builtin_amdgcn_mfma_f32_16x16x32_bf16(afr[kk], bfr[nf][kk], acc[nf], 0, 0, 0);
      const int code0 = st * 128 + wm * 64 + mf * 16;
      #pragma unroll
      for (int nf = 0; nf < 4; ++nf)
        #pragma unroll
        for (int r = 0; r < 4; ++r) {
          float v = acc[nf][r];
          bool gtv = v > rmax[nf];
          rmax[nf] = gtv ? v : rmax[nf];
          ridx[nf] = gtv ? (code0 + r) : ridx[nf];
        }
    }
    __syncthreads();
  }

  // ---- cross-lane reduce (lanes l, l^16, l^32, l^48 share a query column) ----
  const int pslot = c * 2 + wm;
  #pragma unroll
  for (int nf = 0; nf < 4; ++nf) {
    float m = rmax[nf];
    int gi = chunk0 + ridx[nf] + ((lane >> 4) << 2);   // full doc id
    #pragma unroll
    for (int s = 16; s <= 32; s <<= 1) {
      float om = __shfl_xor(m, s);
      int   oi = __shfl_xor(gi, s);
      if (om > m || (om == m && oi < gi)) { m = om; gi = oi; }
    }
    if (lane < 16) {
      int q = qblock + wn * 64 + nf * 16 + lane;
      pmi[pslot * Q_N + q] = make_float2(m, __int_as_float(gi));
    }
  }
}

// ---------------- Kernel C1: reduce partials per query, gather weights, partial sums ----------------
__global__ void reduce_kernel(const float2* __restrict__ pmi,
                              const int* __restrict__ qtok, const int* __restrict__ dtok,
                              const float* __restrict__ qwt, const float* __restrict__ dwt,
                              float* __restrict__ sums) {
  int q = blockIdx.x * 256 + threadIdx.x;
  float m = -3.0e38f; int best = 0;
  #pragma unroll 8
  for (int s = 0; s < NSLOT; ++s) {
    float2 p = pmi[s * Q_N + q];
    int i = __float_as_int(p.y);
    if (p.x > m || (p.x == m && i < best)) { m = p.x; best = i; }
  }
  float cmb = qwt[qtok[q]] * dwt[dtok[best]];
  float s0 = cmb, s1 = m * cmb, s2 = m;
  #pragma unroll
  for (int sh = 32; sh >= 1; sh >>= 1) {
    s0 += __shfl_down(s0, sh);
    s1 += __shfl_down(s1, sh);
    s2 += __shfl_down(s2, sh);
  }
  __shared__ float red[3][4];
  int lane = threadIdx.x & 63, w = threadIdx.x >> 6;
  if (lane == 0) { red[0][w] = s0; red[1][w] = s1; red[2][w] = s2; }
  __syncthreads();
  if (threadIdx.x == 0) {
    atomicAdd(&sums[0], red[0][0] + red[0][1] + red[0][2] + red[0][3]);
    atomicAdd(&sums[1], red[1][0] + red[1][1] + red[1][2] + red[1][3]);
    atomicAdd(&sums[2], red[2][0] + red[2][1] + red[2][2] + red[2][3]);
  }
}

// ---------------- Kernel C2: finalize ----------------
__global__ void finalize_kernel(const float* __restrict__ sums, float* __restrict__ out) {
  float s0 = sums[0], s1 = sums[1], s2 = sums[2];
  out[0] = (s0 > 0.0f) ? (s1 / s0) : (s2 / (float)Q_N);  // zero-sum fallback = uniform
}

// ---------------- Launch ----------------
extern "C" void kernel_launch(void* const* d_in, const int* in_sizes, int n_in,
                              void* d_out, int out_size, void* d_ws, size_t ws_size,
                              hipStream_t stream) {
  const float* qe   = (const float*)d_in[0];
  const float* de   = (const float*)d_in[1];
  const int*   qtok = (const int*)d_in[2];
  const int*   dtok = (const int*)d_in[3];
  const float* qwt  = (const float*)d_in[4];
  const float* dwt  = (const float*)d_in[5];
  float* out = (float*)d_out;

  char* ws = (char*)d_ws;
  ushort* qbf  = (ushort*)(ws + WS_QBF);
  ushort* dbf  = (ushort*)(ws + WS_DBF);
  float2* pmi  = (float2*)(ws + WS_PMI);
  float*  sums = (float*)(ws + WS_SUMS);

  const int NQ4 = Q_N * DIM / 4, ND4 = D_N * DIM / 4;
  convert_kernel<<<(NQ4 + ND4) / 256, 256, 0, stream>>>(qe, de, qbf, dbf, sums);

  maxsim_kernel<<<NQT * NCHUNK, 512, 0, stream>>>(dbf, qbf, pmi);

  reduce_kernel<<<Q_N / 256, 256, 0, stream>>>(pmi, qtok, dtok, qwt, dwt, sums);
  finalize_kernel<<<1, 1, 0, stream>>>(sums, out);
}

// Round 6
// 134.541 us; speedup vs baseline: 1.0328x; 1.0328x over previous
//
#include <hip/hip_runtime.h>
#include <hip/hip_bf16.h>
#include <stdint.h>

// Problem constants
#define Q_N   4096
#define D_N   32768
#define DIM   128
#define VOCAB 32000

#define NCHUNK 32                    // doc chunks
#define CHUNK  (D_N / NCHUNK)        // 1024 docs per chunk
#define QTILE  256                   // queries per block
#define NQT    (Q_N / QTILE)         // 16 q-tiles
#define DSUB   128                   // docs per LDS subtile
#define NSUB   (CHUNK / DSUB)        // 8 subtiles per chunk
#define NSLOT  (NCHUNK * 2)          // partial slots: chunk x wm-strip = 64

typedef short  short8 __attribute__((ext_vector_type(8)));
typedef float  f32x4  __attribute__((ext_vector_type(4)));

// Workspace layout (bytes)
#define WS_QBF  0u                               // 4096*128*2  = 1 MiB
#define WS_DBF  0x100000u                        // 32768*128*2 = 8 MiB
#define WS_PMI  0x900000u                        // 64*4096*8   = 2 MiB (float2: max, idx-bits)
#define WS_SUMS 0xB00000u                        // 4 floats

// ---------------- Kernel A: fp32 -> bf16 convert (+ zero sums) ----------------
__device__ inline ushort f2bf(float f) {
  uint32_t u = __float_as_uint(f);
  u += 0x7FFFu + ((u >> 16) & 1u);   // RNE
  return (ushort)(u >> 16);
}

__global__ void convert_kernel(const float* __restrict__ qe, const float* __restrict__ de,
                               ushort* __restrict__ qb, ushort* __restrict__ db,
                               float* __restrict__ sums) {
  int i = blockIdx.x * 256 + threadIdx.x;
  if (i < 4) sums[i] = 0.0f;         // ws is re-poisoned every launch
  const int NQ4 = Q_N * DIM / 4;     // 131072 float4s
  float4 v;
  ushort* dst;
  if (i < NQ4) {
    v = ((const float4*)qe)[i];
    dst = qb + (size_t)i * 4;
  } else {
    int j = i - NQ4;                 // < 1048576 (grid sized exactly)
    v = ((const float4*)de)[j];
    dst = db + (size_t)j * 4;
  }
  ushort4 o;
  o.x = f2bf(v.x); o.y = f2bf(v.y); o.z = f2bf(v.z); o.w = f2bf(v.w);
  *(ushort4*)dst = o;
}

// Pack a 7-bit element code into the low mantissa bits of v (top 25 bits kept).
// Single v_and_or_b32: S0=v (VGPR), S1=mask (VGPR), S2=code (SGPR, uniform) -> 1 SGPR, legal.
// Quantization: 2^-16 relative (~7e-4 abs on sims ~46) -- negligible vs 0.935 threshold.
__device__ inline float packf(float v, uint32_t vmask, uint32_t code) {
  uint32_t r;
  asm("v_and_or_b32 %0, %1, %2, %3" : "=v"(r) : "v"(v), "v"(vmask), "s"(code));
  return __uint_as_float(r);
}

// ---------------- Kernel B: MaxSim partial (GEMM + row-max epilogue, packed argmax) ----------------
// S^T tiles: M = docs, N = queries, K = 128. A = doc bf16 [D][128] (LDS-staged),
// B = query bf16 [Q][128] (registers). 512 threads = 8 waves as 2M x 4N over a
// 128-doc x 256-query tile: wm = wid>>2 (64-doc strip), wn = wid&3 (64-query strip).
// mfma_f32_16x16x32_bf16 layouts (m89-verified):
//   A[m][k]: m = lane&15, k = (lane>>4)*8 + e
//   B[k][n]: n = lane&15, k = (lane>>4)*8 + e
//   C[r]:    col = lane&15, row = (lane>>4)*4 + r
// Running reduction is pure v_max3 on code-packed values; code = st*16 + mf*4 + r
// (7 bits). Decode at exit: doc = chunk0 + st*128 + wm*64 + mf*16 + (lane>>4)*4 + r.
// Block mapping concentrates each chunk's 16 q-tile blocks on ONE XCD (L2-resident).
__global__ __launch_bounds__(512, 2)
void maxsim_kernel(const ushort* __restrict__ dbf, const ushort* __restrict__ qbf,
                   float2* __restrict__ pmi) {
  __shared__ ushort lds[2][DSUB * DIM];   // 2 x 32 KiB, double-buffered doc tile

  const int tid  = threadIdx.x;
  const int lane = tid & 63;
  const int wid  = tid >> 6;
  const int wm   = wid >> 2;              // doc strip: rows [wm*64, wm*64+64)
  const int wn   = wid & 3;               // query strip: cols [wn*64, wn*64+64)

  // XCD-concentrated (chunk, qtile) mapping: bijective over 512 blocks
  const int bid  = blockIdx.x;
  const int xcd  = bid & 7;
  const int slot = bid >> 3;              // [0,64)
  const int c    = xcd + 8 * (slot >> 4); // chunk id: 4 per XCD
  const int qt   = slot & 15;
  const int qblock = qt * QTILE;
  const int chunk0 = c * CHUNK;

  // ---- B fragments (queries) from global, held in registers: 64 VGPR ----
  short8 bfr[4][4];                       // [nf][kk]
  #pragma unroll
  for (int nf = 0; nf < 4; ++nf) {
    int qrow = qblock + wn * 64 + nf * 16 + (lane & 15);
    const ushort* p = qbf + (size_t)qrow * DIM + ((lane >> 4) * 8);
    #pragma unroll
    for (int kk = 0; kk < 4; ++kk)
      bfr[nf][kk] = *(const short8*)(p + kk * 32);
  }

  const uint32_t vmask = 0xFFFFFF80u;     // materialized once into a VGPR by constraint
  float rmax[4];
  #pragma unroll
  for (int nf = 0; nf < 4; ++nf) rmax[nf] = -3.0e38f;

  const char* gdoc = (const char*)(dbf + (size_t)chunk0 * DIM);

  // Precomputed stage offsets (constant across subtiles).
  // LDS dest is linear (global_load_lds writes wave-uniform base + lane*16);
  // XOR swizzle (byte ^= ((row&7)<<4)) applied to GLOBAL source and on ds_read.
  int swzoff[4];
  #pragma unroll
  for (int it = 0; it < 4; ++it) {
    int o = wid * 4096 + it * 1024 + lane * 16;
    swzoff[it] = o ^ (((o >> 8) & 7) << 4);
  }

  auto stage = [&](int b, int st) {
    const char* gt = gdoc + st * (DSUB * DIM * 2);
    char* lb = (char*)&lds[b][0] + wid * 4096;
    #pragma unroll
    for (int it = 0; it < 4; ++it) {
      __builtin_amdgcn_global_load_lds(
          (const __attribute__((address_space(1))) uint32_t*)(gt + swzoff[it]),
          (__attribute__((address_space(3))) uint32_t*)(lb + it * 1024),
          16, 0, 0);
    }
  };

  stage(0, 0);
  __syncthreads();

  #pragma unroll 1
  for (int st = 0; st < NSUB; ++st) {     // 8 subtiles of 128 docs
    const int b = st & 1;
    if (st + 1 < NSUB) stage(b ^ 1, st + 1);

    const char* lb = (const char*)&lds[b][0];
    const uint32_t stcode = (uint32_t)(st * 16);
    #pragma unroll
    for (int mf = 0; mf < 4; ++mf) {
      short8 afr[4];
      int arow = wm * 64 + mf * 16 + (lane & 15);
      #pragma unroll
      for (int kk = 0; kk < 4; ++kk) {
        int abyte = (arow * 256 + kk * 64 + ((lane >> 4) * 16)) ^ ((arow & 7) << 4);
        afr[kk] = *(const short8*)(lb + abyte);
      }
      // 4 independent accumulator chains (nf inner) pipeline the MFMA latency
      f32x4 acc[4];
      #pragma unroll
      for (int nf = 0; nf < 4; ++nf) acc[nf] = (f32x4){0.f, 0.f, 0.f, 0.f};
      #pragma unroll
      for (int kk = 0; kk < 4; ++kk)
        #pragma unroll
        for (int nf = 0; nf < 4; ++nf)
          acc[nf] = __builtin_amdgcn_mfma_f32_16x16x32_bf16(afr[kk], bfr[nf][kk], acc[nf], 0, 0, 0);
      // pack element code into low 7 mantissa bits; reduce with v_max3 chains
      const uint32_t code0 = stcode + (uint32_t)(mf * 4);
      #pragma unroll
      for (int nf = 0; nf < 4; ++nf) {
        float p0 = packf(acc[nf][0], vmask, code0 + 0);
        float p1 = packf(acc[nf][1], vmask, code0 + 1);
        float p2 = packf(acc[nf][2], vmask, code0 + 2);
        float p3 = packf(acc[nf][3], vmask, code0 + 3);
        float t  = fmaxf(fmaxf(p0, p1), p2);            // v_max3
        rmax[nf] = fmaxf(fmaxf(p3, rmax[nf]), t);       // v_max3
      }
    }
    __syncthreads();
  }

  // ---- decode packed code, then cross-lane reduce (lanes l, l^16, l^32, l^48) ----
  const int pslot = c * 2 + wm;
  #pragma unroll
  for (int nf = 0; nf < 4; ++nf) {
    float m = rmax[nf];
    uint32_t codebits = __float_as_uint(m) & 0x7Fu;
    int stv = (int)(codebits >> 4);
    int mfv = (int)((codebits >> 2) & 3u);
    int rv  = (int)(codebits & 3u);
    int gi  = chunk0 + stv * 128 + wm * 64 + mfv * 16 + ((lane >> 4) << 2) + rv;
    #pragma unroll
    for (int s = 16; s <= 32; s <<= 1) {
      float om = __shfl_xor(m, s);
      int   oi = __shfl_xor(gi, s);
      if (om > m || (om == m && oi < gi)) { m = om; gi = oi; }
    }
    if (lane < 16) {
      int q = qblock + wn * 64 + nf * 16 + lane;
      pmi[pslot * Q_N + q] = make_float2(m, __int_as_float(gi));
    }
  }
}

// ---------------- Kernel C1: reduce partials per query, gather weights, partial sums ----------------
__global__ void reduce_kernel(const float2* __restrict__ pmi,
                              const int* __restrict__ qtok, const int* __restrict__ dtok,
                              const float* __restrict__ qwt, const float* __restrict__ dwt,
                              float* __restrict__ sums) {
  int q = blockIdx.x * 256 + threadIdx.x;
  float m = -3.0e38f; int best = 0;
  #pragma unroll 8
  for (int s = 0; s < NSLOT; ++s) {
    float2 p = pmi[s * Q_N + q];
    int i = __float_as_int(p.y);
    if (p.x > m || (p.x == m && i < best)) { m = p.x; best = i; }
  }
  float cmb = qwt[qtok[q]] * dwt[dtok[best]];
  float s0 = cmb, s1 = m * cmb, s2 = m;
  #pragma unroll
  for (int sh = 32; sh >= 1; sh >>= 1) {
    s0 += __shfl_down(s0, sh);
    s1 += __shfl_down(s1, sh);
    s2 += __shfl_down(s2, sh);
  }
  __shared__ float red[3][4];
  int lane = threadIdx.x & 63, w = threadIdx.x >> 6;
  if (lane == 0) { red[0][w] = s0; red[1][w] = s1; red[2][w] = s2; }
  __syncthreads();
  if (threadIdx.x == 0) {
    atomicAdd(&sums[0], red[0][0] + red[0][1] + red[0][2] + red[0][3]);
    atomicAdd(&sums[1], red[1][0] + red[1][1] + red[1][2] + red[1][3]);
    atomicAdd(&sums[2], red[2][0] + red[2][1] + red[2][2] + red[2][3]);
  }
}

// ---------------- Kernel C2: finalize ----------------
__global__ void finalize_kernel(const float* __restrict__ sums, float* __restrict__ out) {
  float s0 = sums[0], s1 = sums[1], s2 = sums[2];
  out[0] = (s0 > 0.0f) ? (s1 / s0) : (s2 / (float)Q_N);  // zero-sum fallback = uniform
}

// ---------------- Launch ----------------
extern "C" void kernel_launch(void* const* d_in, const int* in_sizes, int n_in,
                              void* d_out, int out_size, void* d_ws, size_t ws_size,
                              hipStream_t stream) {
  const float* qe   = (const float*)d_in[0];
  const float* de   = (const float*)d_in[1];
  const int*   qtok = (const int*)d_in[2];
  const int*   dtok = (const int*)d_in[3];
  const float* qwt  = (const float*)d_in[4];
  const float* dwt  = (const float*)d_in[5];
  float* out = (float*)d_out;

  char* ws = (char*)d_ws;
  ushort* qbf  = (ushort*)(ws + WS_QBF);
  ushort* dbf  = (ushort*)(ws + WS_DBF);
  float2* pmi  = (float2*)(ws + WS_PMI);
  float*  sums = (float*)(ws + WS_SUMS);

  const int NQ4 = Q_N * DIM / 4, ND4 = D_N * DIM / 4;
  convert_kernel<<<(NQ4 + ND4) / 256, 256, 0, stream>>>(qe, de, qbf, dbf, sums);

  maxsim_kernel<<<NQT * NCHUNK, 512, 0, stream>>>(dbf, qbf, pmi);

  reduce_kernel<<<Q_N / 256, 256, 0, stream>>>(pmi, qtok, dtok, qwt, dwt, sums);
  finalize_kernel<<<1, 1, 0, stream>>>(sums, out);
}